// Round 9
// baseline (503.480 us; speedup 1.0000x reference)
//
#include <hip/hip_runtime.h>
#include <hip/hip_bf16.h>
#include <math.h>

#define NB 4
#define NC 16
#define NN 8192
#define NK 9
#define LIST 12            /* in-register per-sublist top-K (margin over 9) */
#define LOUT 10            /* entries written per sublist (16 sublists/row) */
#define CANDN (16 * LOUT)  /* 160 union candidates per row */
#define CAP 16             /* LDS stack slots per lane */
#define MR (NN / 4)        /* m-range per wave (4 qsplit waves per block) */

typedef short s16x8 __attribute__((ext_vector_type(8)));
typedef float f32x4 __attribute__((ext_vector_type(4)));

// ws layout (bytes): xt f32[4][8192][16] | xs bf16-split[4][8192][32] |
// ns32 | nk | nbr u16[32768][9] | cand u16[32768][160]
#define OFF_XS   2097152u
#define OFF_NS   (OFF_XS + 2097152u)
#define OFF_NK   (OFF_NS + 131072u)
#define OFF_NBR  (OFF_NK + 131072u)
#define OFF_CAND (OFF_NBR + 589824u)   /* total 15532032 <= proven ws >= 15728640 */

// ---------------------------------------------------------------------------
// Kernel 0: xt = transposed f32 (rerank/conv); ns32 = numpy-replica norm
// (squares rounded, sequential adds, no FMA — verified R3); nk = 128+0.5*ns
// (always-positive surrogate offset); xs = bf16 hi/lo split [m][hi*16,lo*16]
// (64B rows: MFMA A/B fragment source).
// ---------------------------------------------------------------------------
__global__ void prep_kernel(const float* __restrict__ x,
                            float* __restrict__ xt,
                            float* __restrict__ ns32,
                            float* __restrict__ nk,
                            unsigned short* __restrict__ xs) {
    int t = blockIdx.x * 256 + threadIdx.x;   // 0..32767
    int b = t >> 13, m = t & (NN - 1);
    const float* xb = x + (size_t)b * NC * NN;
    float v[NC];
#pragma unroll
    for (int c = 0; c < NC; ++c) v[c] = xb[(size_t)c * NN + m];  // coalesced
    float s = __fmul_rn(v[0], v[0]);
#pragma unroll
    for (int c = 1; c < NC; ++c) s = __fadd_rn(s, __fmul_rn(v[c], v[c]));
    float* o = xt + (size_t)t * NC;
#pragma unroll
    for (int c = 0; c < NC; ++c) o[c] = v[c];
    ns32[t] = s;
    nk[t] = 128.0f + 0.5f * s;
    unsigned short* xo = xs + (size_t)t * 32;
#pragma unroll
    for (int c = 0; c < NC; ++c) {
        __hip_bfloat16 h = __float2bfloat16(v[c]);
        float hf = __bfloat162float(h);
        __hip_bfloat16 l = __float2bfloat16(v[c] - hf);
        xo[c] = *(unsigned short*)&h;
        xo[16 + c] = *(unsigned short*)&l;
    }
}

// Sorted (ascending) 12-slot u64 bubble insert; inserting ~0ULL is a no-op.
__device__ __forceinline__ void insert12(unsigned long long* lst,
                                         unsigned long long key) {
#pragma unroll
    for (int i = 0; i < LIST; ++i) {
        unsigned long long a = lst[i];
        bool sm = key < a;
        unsigned long long lo = sm ? key : a;
        key = sm ? a : key;
        lst[i] = lo;
    }
}

__device__ __forceinline__ s16x8 negbf(s16x8 v) {   // bf16 sign flip
    s16x8 r;
#pragma unroll
    for (int i = 0; i < 8; ++i) r[i] = (short)(v[i] ^ (short)0x8000);
    return r;
}

// ---------------------------------------------------------------------------
// Kernel 1: MFMA surrogate top-K. Block = 32 rows x full m (4 waves = 4
// m-quarters). Wave = 2 n-tiles (16 rows each). Per 16m tile: A = x-split[m]
// (K=32: hi||lo), B = dup-negated {hi,lo} of the wave's rows, C-init = nk[m]
// -> acc[r] IS the surrogate key nk[m] - x_m.x_n (error ~1e-4 << rank gaps).
// Keys pushed branchlessly to a per-lane LDS stack (write-at-slot, advance
// stkoff on hit k32 <= thr); flush-on-demand does __any-guarded insert12 and
// refreshes thr = min(own 12th, 4-lane shfl-min, per-row LDS atomicMin cell)
// -- thr >= true row 12th at all times => union over 16 sublists contains the
// surrogate top-12 => deterministic, rerank-safe.
// ---------------------------------------------------------------------------
__global__ __launch_bounds__(256, 4) void topk_kernel(
        const unsigned short* __restrict__ xs, const float* __restrict__ nk,
        unsigned short* __restrict__ cand) {
    __shared__ unsigned thrLDS[32];
    __shared__ unsigned long long stk[CAP * 256];
    const int tid = threadIdx.x;
    const int L = tid & 63;
    const int q = tid >> 6;                 // wave id = m-quarter
    const int b = blockIdx.x >> 8;          // batch
    const int n0 = (blockIdx.x & 255) * 32; // block's 32-row group
    const int lrow = L & 15;
    const int lk = L >> 4;                  // 0..3 (k-group / acc m-group)
    if (tid < 32) thrLDS[tid] = 0xFFFFFFFFu;
    __syncthreads();

    const char* xsb = (const char*)xs + (size_t)b * NN * 64;
    const char* nkb = (const char*)(nk + (size_t)b * NN);

    // B fragments (negated) for the wave's two 16-row tiles.
    const int khalf = (lk & 1) * 16;
    const int r0 = n0 + lrow, r1 = n0 + 16 + lrow;
    s16x8 bhi0 = negbf(*(const s16x8*)(xsb + (size_t)r0 * 64 + khalf));
    s16x8 blo0 = negbf(*(const s16x8*)(xsb + (size_t)r0 * 64 + 32 + khalf));
    s16x8 bhi1 = negbf(*(const s16x8*)(xsb + (size_t)r1 * 64 + khalf));
    s16x8 blo1 = negbf(*(const s16x8*)(xsb + (size_t)r1 * 64 + 32 + khalf));

    unsigned long long lst0[LIST], lst1[LIST];
#pragma unroll
    for (int i = 0; i < LIST; ++i) { lst0[i] = ~0ULL; lst1[i] = ~0ULL; }

    const int m0 = q * MR;
    int voffA = (m0 + lrow) * 64 + lk * 16;   // byte offset into xs batch
    int voffK = (m0 + lk * 4) * 4;            // byte offset into nk batch
    const unsigned stkbase = (unsigned)tid * 8u;
    const unsigned stklim = stkbase + (CAP - 8) * 2048u;
    unsigned stkoff = stkbase;
    unsigned thr0 = 0xFFFFFFFFu, thr1 = 0xFFFFFFFFu;

    auto flush = [&]() {
        int cnt = (int)((stkoff - stkbase) >> 11);
        int s = 0;
        while (__any(s < cnt)) {
            const unsigned long long e =
                *(const unsigned long long*)((const char*)stk + stkbase +
                                             (unsigned)s * 2048u);
            const bool act = s < cnt;
            const unsigned k32 = (unsigned)(e >> 32);
            const unsigned meta = (unsigned)e;
            const int ntb = (meta >> 2) & 1;
            const unsigned m = (unsigned)(m0 + (int)(meta >> 3) * 16 +
                                          lk * 4 + (int)(meta & 3u));
            const unsigned long long key = ((unsigned long long)k32 << 32) | m;
            const bool v0 = act && !ntb && k32 < (unsigned)(lst0[LIST - 1] >> 32);
            const bool v1 = act && ntb && k32 < (unsigned)(lst1[LIST - 1] >> 32);
            if (__any(v0)) insert12(lst0, v0 ? key : ~0ULL);
            if (__any(v1)) insert12(lst1, v1 ? key : ~0ULL);
            ++s;
        }
        stkoff = stkbase;
        unsigned t0 = (unsigned)(lst0[LIST - 1] >> 32);
        unsigned t1 = (unsigned)(lst1[LIST - 1] >> 32);
        unsigned u;
        u = __shfl_xor(t0, 16); t0 = t0 < u ? t0 : u;
        u = __shfl_xor(t0, 32); t0 = t0 < u ? t0 : u;
        u = __shfl_xor(t1, 16); t1 = t1 < u ? t1 : u;
        u = __shfl_xor(t1, 32); t1 = t1 < u ? t1 : u;
        if (L < 16) {
            atomicMin(&thrLDS[lrow], t0);
            atomicMin(&thrLDS[16 + lrow], t1);
        }
        unsigned s0 = *(volatile unsigned*)&thrLDS[lrow];
        unsigned s1 = *(volatile unsigned*)&thrLDS[16 + lrow];
        thr0 = t0 < s0 ? t0 : s0;
        thr1 = t1 < s1 ? t1 : s1;
    };

    for (int t = 0; t < MR / 16; ++t) {
        const s16x8 a = *(const s16x8*)(xsb + voffA);
        const f32x4 nkv = *(const f32x4*)(nkb + voffK);
        f32x4 acc0 = __builtin_amdgcn_mfma_f32_16x16x32_bf16(a, bhi0, nkv, 0, 0, 0);
        acc0 = __builtin_amdgcn_mfma_f32_16x16x32_bf16(a, blo0, acc0, 0, 0, 0);
        f32x4 acc1 = __builtin_amdgcn_mfma_f32_16x16x32_bf16(a, bhi1, nkv, 0, 0, 0);
        acc1 = __builtin_amdgcn_mfma_f32_16x16x32_bf16(a, blo1, acc1, 0, 0, 0);
#pragma unroll
        for (int r = 0; r < 4; ++r) {
            const unsigned k32 = __float_as_uint(acc0[r]);
            *(unsigned long long*)((char*)stk + stkoff) =
                ((unsigned long long)k32 << 32) | (unsigned)((t << 3) | r);
            stkoff += (k32 <= thr0) ? 2048u : 0u;
        }
#pragma unroll
        for (int r = 0; r < 4; ++r) {
            const unsigned k32 = __float_as_uint(acc1[r]);
            *(unsigned long long*)((char*)stk + stkoff) =
                ((unsigned long long)k32 << 32) | (unsigned)((t << 3) | 4 | r);
            stkoff += (k32 <= thr1) ? 2048u : 0u;
        }
        if (__any(stkoff >= stklim)) flush();
        voffA += 1024;
        voffK += 64;
    }
    flush();

    const int grow0 = b * NN + r0;
    const int grow1 = b * NN + r1;
    unsigned short* o0 = cand + (size_t)grow0 * CANDN + (q * 4 + lk) * LOUT;
    unsigned short* o1 = cand + (size_t)grow1 * CANDN + (q * 4 + lk) * LOUT;
#pragma unroll
    for (int i = 0; i < LOUT; ++i) {
        o0[i] = (unsigned short)(lst0[i] & 0xFFFFu);
        o1[i] = (unsigned short)(lst1[i] & 0xFFFFu);
    }
}

// ---------------------------------------------------------------------------
// Kernel 2: exact re-rank of the 160 union candidates with the BIT-EXACT
// numpy-f32 replica distance (verified R3): dot = sequential fmaf chain;
// dist = fl(fl(ns_n+ns_m) - fl(2*dot)), max(dist,0); diag k32=0; sentinel
// (m >= NN) k32=~0. Stable (dist, idx) top-9 -> 9 neighbor indices per row.
// ---------------------------------------------------------------------------
template <int CN>
__global__ __launch_bounds__(256) void rerank_kernel(
        const float* __restrict__ xt, const float* __restrict__ ns32,
        const unsigned short* __restrict__ cand,
        unsigned short* __restrict__ nbr) {
    const int row = blockIdx.x * 256 + threadIdx.x;
    const int b = row >> 13;
    const int n = row & (NN - 1);
    const float* xb = xt + (size_t)b * NN * NC;
    const float* xrow = xb + (size_t)n * NC;
    float xv[NC];
#pragma unroll
    for (int c = 0; c < NC; ++c) xv[c] = xrow[c];
    const float nsn = ns32[row];
    const float* nsb = ns32 + b * NN;

    unsigned long long lst[NK];
#pragma unroll
    for (int i = 0; i < NK; ++i) lst[i] = ~0ULL;

    const unsigned short* cl = cand + (size_t)row * CN;
    for (int j = 0; j < CN; ++j) {
        const int m = cl[j];
        const float* col = xb + (size_t)(m & (NN - 1)) * NC;
        float dot = 0.0f;
#pragma unroll
        for (int c = 0; c < NC; ++c)
            dot = fmaf(xv[c], col[c], dot);   // npyv_muladd replica (FMA)
        float dist = __fsub_rn(__fadd_rn(nsn, nsb[m & (NN - 1)]),
                               __fmul_rn(2.0f, dot));
        dist = fmaxf(dist, 0.0f);
        unsigned k32 = (m == n) ? 0u : (__float_as_uint(dist) | 0x80000000u);
        if (m >= NN) k32 = 0xFFFFFFFFu;       // sentinel slot: never selected
        unsigned long long key = ((unsigned long long)k32 << 32) | (unsigned)m;
        if (key < lst[NK - 1]) {
#pragma unroll
            for (int i = 0; i < NK; ++i) {
                unsigned long long aa = lst[i];
                bool sm = key < aa;
                unsigned long long lo = sm ? key : aa;
                unsigned long long hi = sm ? aa : key;
                lst[i] = lo;
                key = hi;
            }
        }
    }
    unsigned short* o = nbr + (size_t)row * NK;
#pragma unroll
    for (int k = 0; k < NK; ++k) o[k] = (unsigned short)(lst[k] & 0xFFFFu);
}

// ---------------------------------------------------------------------------
// Kernel 3: conv epilogue. Block-uniform output channel -> scalar W/bias.
// ---------------------------------------------------------------------------
__global__ __launch_bounds__(256) void conv_kernel(
        const float* __restrict__ xt, const unsigned short* __restrict__ nbr,
        const float* __restrict__ W, const float* __restrict__ bias,
        float* __restrict__ out) {
    const int tid = threadIdx.x;
    const int ob = blockIdx.x >> 7;       // 0..15, uniform
    const int rb = blockIdx.x & 127;
    const int row = rb * 256 + tid;
    const int b = rb >> 5;                // uniform
    const int n = row & (NN - 1);
    const float* xb = xt + (size_t)b * NN * NC;
    const float* Wo = W + ob * (NC * NK); // uniform
    const unsigned short* nl = nbr + (size_t)row * NK;

    float acc = bias[ob];
    for (int k = 0; k < NK; ++k) {
        const float* col = xb + (size_t)nl[k] * NC;
        float cv[NC];
#pragma unroll
        for (int c = 0; c < NC; ++c) cv[c] = col[c];
#pragma unroll
        for (int c = 0; c < NC; ++c)
            acc = fmaf(Wo[c * NK + k], cv[c], acc);
    }
    out[(size_t)b * NC * NN + (size_t)ob * NN + n] = acc;
}

extern "C" void kernel_launch(void* const* d_in, const int* in_sizes, int n_in,
                              void* d_out, int out_size, void* d_ws, size_t ws_size,
                              hipStream_t stream) {
    const float* x = (const float*)d_in[0];     // [4][16][8192]
    const float* W = (const float*)d_in[1];     // [16][16][9]
    const float* bias = (const float*)d_in[2];  // [16]
    float* out = (float*)d_out;                 // [4][16][8192]

    char* ws = (char*)d_ws;
    float* xt = (float*)ws;
    unsigned short* xs = (unsigned short*)(ws + OFF_XS);
    float* ns32 = (float*)(ws + OFF_NS);
    float* nk = (float*)(ws + OFF_NK);
    unsigned short* nbr = (unsigned short*)(ws + OFF_NBR);
    unsigned short* cand = (unsigned short*)(ws + OFF_CAND);

    prep_kernel<<<128, 256, 0, stream>>>(x, xt, ns32, nk, xs);
    topk_kernel<<<1024, 256, 0, stream>>>(xs, nk, cand);
    rerank_kernel<CANDN><<<128, 256, 0, stream>>>(xt, ns32, cand, nbr);
    conv_kernel<<<2048, 256, 0, stream>>>(xt, nbr, W, bias, out);
}